// Round 13
// baseline (135.394 us; speedup 1.0000x reference)
//
#include <hip/hip_runtime.h>

#define H_ 480
#define W_ 640
#define HW 307200
#define NN 128
#define QQ 8192
#define KK 10
#define G_ 6
#define PIXB 6144   // legacy path: 256 threads * 4 px * G_ iters

// ws layout (bytes)
#define WS_FLAG   0
#define WS_ACC    64            // 128*12 floats = 6144 B
#define WS_ABD    8192          // 128*8 floats  = 4096 B
#define WS_VBITS  16384         // 4800 * 8      = 38400 B
#define WS_PRIO   65536         // 307200*4 = 1228800 B
#define WS_PACK   1294336       // NN*38400 = 4915200 B (1 byte per 8 px)
#define WS_NEED   (WS_PACK + (size_t)NN * 38400)

#define CBLK 2400               // 2400*256*8 = NN*HW/8 groups exactly

typedef unsigned int u32x4 __attribute__((ext_vector_type(4)));

// ---- prep: detect mask format (block 0), pack valid bits, zero prio/acc ---
__global__ __launch_bounds__(256) void prep_k(const unsigned int* __restrict__ gm,
                                              const float* __restrict__ gtd,
                                              unsigned long long* __restrict__ vbits,
                                              int* __restrict__ prio,
                                              float* __restrict__ acc,
                                              int* __restrict__ flag)
{
    const int pix = blockIdx.x * 256 + threadIdx.x;
    prio[pix] = 0;
    if (pix < NN * 12) acc[pix] = 0.0f;
    const bool v = gtd[pix] > 0.1f;
    const unsigned long long b = __ballot(v);
    if ((threadIdx.x & 63) == 0) vbits[pix >> 6] = b;

    if (blockIdx.x == 0) {
        // int32: every word 0/1. uint8: words >1 (but != 0x3F800000) common.
        // float32: words 0x0 or 0x3F800000.
        __shared__ int sf;
        if (threadIdx.x == 0) sf = 0;
        __syncthreads();
        int f = 0;
        for (int i = threadIdx.x; i < 4096; i += 256) {
            const unsigned int w = gm[i];
            if (w == 0x3F800000u) f |= 2;
            else if (w > 1u) f |= 1;
        }
        if (f) atomicOr(&sf, f);
        __syncthreads();
        if (threadIdx.x == 0) *flag = (sf & 2) ? 2 : ((sf & 1) ? 1 : 0);
    }
}

__device__ __forceinline__ unsigned byte8(const u32x4 a0, const u32x4 a1)
{
    return (a0.x ? 0x01u : 0u) | (a0.y ? 0x02u : 0u)
         | (a0.z ? 0x04u : 0u) | (a0.w ? 0x08u : 0u)
         | (a1.x ? 0x10u : 0u) | (a1.y ? 0x20u : 0u)
         | (a1.z ? 0x40u : 0u) | (a1.w ? 0x80u : 0u);
}

__device__ __forceinline__ unsigned byteU64(const unsigned long long v)
{
    unsigned m = 0;
    #pragma unroll
    for (int j = 0; j < 8; ++j)
        m |= (unsigned)(((v >> (8*j)) & 0xFFull) != 0) << j;
    return m;
}

// ---- pass 1a: SINGLE-stream — gm -> 1 byte per 8 px -----------------------
// m13/fill-shaped: one read stream, dense, 2400x256 thr, exactly 8 iters.
__global__ __launch_bounds__(256) void compressA_k(
    const void* __restrict__ gmv,
    const int* __restrict__ flag,
    unsigned char* __restrict__ packed)
{
    const int fmt = *flag;
    const int t0 = blockIdx.x * 256 + (int)threadIdx.x;
    const int stride = CBLK * 256;

    if (fmt != 1) {
        const u32x4* __restrict__ gp = (const u32x4*)gmv;
        #pragma unroll 2
        for (int k = 0; k < 8; ++k) {
            const int g = t0 + k * stride;               // byte-group, 8 px
            const u32x4 a0 = __builtin_nontemporal_load(gp + 2*g);
            const u32x4 a1 = __builtin_nontemporal_load(gp + 2*g + 1);
            packed[g] = (unsigned char)byte8(a0, a1);
        }
    } else {
        const unsigned long long* __restrict__ gp = (const unsigned long long*)gmv;
        #pragma unroll 2
        for (int k = 0; k < 8; ++k) {
            const int g = t0 + k * stride;
            packed[g] = (unsigned char)byteU64(__builtin_nontemporal_load(gp + g));
        }
    }
}

// ---- pass 1b: SINGLE-stream — rm AND into packed --------------------------
__global__ __launch_bounds__(256) void compressB_k(
    const void* __restrict__ rmv,
    const int* __restrict__ flag,
    unsigned char* __restrict__ packed)
{
    const int fmt = *flag;
    const int t0 = blockIdx.x * 256 + (int)threadIdx.x;
    const int stride = CBLK * 256;

    if (fmt != 1) {
        const u32x4* __restrict__ rp = (const u32x4*)rmv;
        #pragma unroll 2
        for (int k = 0; k < 8; ++k) {
            const int g = t0 + k * stride;
            const u32x4 b0 = __builtin_nontemporal_load(rp + 2*g);
            const u32x4 b1 = __builtin_nontemporal_load(rp + 2*g + 1);
            packed[g] = (unsigned char)(byte8(b0, b1) & packed[g]);
        }
    } else {
        const unsigned long long* __restrict__ rp = (const unsigned long long*)rmv;
        #pragma unroll 2
        for (int k = 0; k < 8; ++k) {
            const int g = t0 + k * stride;
            packed[g] = (unsigned char)(byteU64(__builtin_nontemporal_load(rp + g)) & packed[g]);
        }
    }
}

// ---- pass 2: per (word-chunk, n) accumulate M, rhs from packed bytes ------
// grid (25, NN), 192 threads; one u64 word (64 px) per thread. 25*192=4800.
__global__ __launch_bounds__(192) void reduce2_k(
    const float* __restrict__ d0,
    const unsigned long long* __restrict__ packed,
    const unsigned long long* __restrict__ vbits,
    const float* __restrict__ km,
    float* __restrict__ acc)
{
    const int n = blockIdx.y;
    const int w = blockIdx.x * 192 + (int)threadIdx.x;   // word index, 0..4799
    unsigned long long bits = packed[(size_t)n * 4800 + w] & vbits[w];
    const float rfx = 1.0f / km[0], rfy = 1.0f / km[4];

    float s0=0.f,s1=0.f,s2=0.f,s3=0.f,s4=0.f,s5=0.f,s6=0.f,s7=0.f,s8=0.f;
    if (bits) {
        const int r = w / 10;                  // 10 words per row (640/64)
        const int c0 = (w - r * 10) * 64;
        const float pyb = (float)(r - 240) * rfy;
        const float* drow = d0 + r * W_ + c0;
        while (bits) {
            const int j = __ffsll((unsigned long long)bits) - 1;
            bits &= bits - 1;
            const float d = drow[j];
            const float ad = fabsf(d);
            const float px = (float)(c0 + j - 320) * ad * rfx;
            const float py = pyb * ad;
            s0 += px*px; s1 += px*py; s2 += px;
            s3 += py*py; s4 += py;    s5 += 1.0f;
            s6 += px*d;  s7 += py*d;  s8 += d;
        }
    }

    float s[9] = {s0,s1,s2,s3,s4,s5,s6,s7,s8};
    #pragma unroll
    for (int off = 32; off > 0; off >>= 1) {
        #pragma unroll
        for (int i = 0; i < 9; ++i) s[i] += __shfl_down(s[i], off);
    }
    __shared__ float ls[3][9];
    const int wave = threadIdx.x >> 6, lane = threadIdx.x & 63;
    if (lane == 0) {
        #pragma unroll
        for (int i = 0; i < 9; ++i) ls[wave][i] = s[i];
    }
    __syncthreads();
    if (threadIdx.x < 9) {
        const int i = threadIdx.x;
        atomicAdd(&acc[n*12 + i], ls[0][i] + ls[1][i] + ls[2][i]);
    }
}

// ---- legacy fused reduction (fallback if ws too small) --------------------
__global__ __launch_bounds__(256) void reduce_k(
    const float* __restrict__ d0,
    const void* __restrict__ gmv,
    const void* __restrict__ rmv,
    const float* __restrict__ km,
    const int* __restrict__ flag,
    const unsigned long long* __restrict__ vbits,
    float* __restrict__ acc)
{
    const int n = blockIdx.y;
    const int base = blockIdx.x * PIXB + (int)threadIdx.x * 4;
    const int fmt = *flag;
    const float rfx = 1.0f / km[0], rfy = 1.0f / km[4];
    const size_t moff = (size_t)n * HW;

    unsigned bitsArr[G_];
    if (fmt != 1) {
        uint4 ga[G_], ra[G_];
        #pragma unroll
        for (int g = 0; g < G_; ++g) {
            const int p = base + g * 1024;
            ga[g] = *reinterpret_cast<const uint4*>((const unsigned*)gmv + moff + p);
            ra[g] = *reinterpret_cast<const uint4*>((const unsigned*)rmv + moff + p);
        }
        #pragma unroll
        for (int g = 0; g < G_; ++g) {
            bitsArr[g] = ((ga[g].x & ra[g].x) ? 1u : 0u) | ((ga[g].y & ra[g].y) ? 2u : 0u)
                       | ((ga[g].z & ra[g].z) ? 4u : 0u) | ((ga[g].w & ra[g].w) ? 8u : 0u);
        }
    } else {
        unsigned ga[G_], ra[G_];
        #pragma unroll
        for (int g = 0; g < G_; ++g) {
            const int p = base + g * 1024;
            ga[g] = *reinterpret_cast<const unsigned*>((const unsigned char*)gmv + moff + p);
            ra[g] = *reinterpret_cast<const unsigned*>((const unsigned char*)rmv + moff + p);
        }
        #pragma unroll
        for (int g = 0; g < G_; ++g) {
            const unsigned ab = ga[g] & ra[g];
            bitsArr[g] = (unsigned)((ab & 0xFFu) != 0) | ((unsigned)(((ab>>8) & 0xFFu) != 0) << 1)
                       | ((unsigned)(((ab>>16) & 0xFFu) != 0) << 2) | ((unsigned)((ab>>24) != 0) << 3);
        }
    }

    float s0=0.f,s1=0.f,s2=0.f,s3=0.f,s4=0.f,s5=0.f,s6=0.f,s7=0.f,s8=0.f;
    #pragma unroll
    for (int g = 0; g < G_; ++g) {
        const int p0 = base + g * 1024;
        unsigned bits = bitsArr[g] & ((unsigned)(vbits[p0 >> 6] >> (p0 & 63)) & 0xFu);
        if (bits) {
            const float4 dv = *reinterpret_cast<const float4*>(d0 + p0);
            const int r = p0 / W_;
            const int c0 = p0 - r * W_;
            const float pyb = (float)(r - 240) * rfy;
            while (bits) {
                const int j = __ffs(bits) - 1;
                bits &= bits - 1;
                const float d = (j == 0) ? dv.x : (j == 1) ? dv.y : (j == 2) ? dv.z : dv.w;
                const float ad = fabsf(d);
                const float px = (float)(c0 + j - 320) * ad * rfx;
                const float py = pyb * ad;
                s0 += px*px; s1 += px*py; s2 += px;
                s3 += py*py; s4 += py;    s5 += 1.0f;
                s6 += px*d;  s7 += py*d;  s8 += d;
            }
        }
    }

    float s[9] = {s0,s1,s2,s3,s4,s5,s6,s7,s8};
    #pragma unroll
    for (int off = 32; off > 0; off >>= 1) {
        #pragma unroll
        for (int i = 0; i < 9; ++i) s[i] += __shfl_down(s[i], off);
    }
    __shared__ float ls[4][9];
    const int wave = threadIdx.x >> 6, lane = threadIdx.x & 63;
    if (lane == 0) {
        #pragma unroll
        for (int i = 0; i < 9; ++i) ls[wave][i] = s[i];
    }
    __syncthreads();
    if (threadIdx.x == 0) {
        #pragma unroll
        for (int i = 0; i < 9; ++i)
            atomicAdd(&acc[n*12 + i], ls[0][i] + ls[1][i] + ls[2][i] + ls[3][i]);
    }
}

// ---- per-n 3x3 solve (Cramer, double), ok gate, mean(pd/den) --------------
__global__ void solve_k(const float* __restrict__ acc,
                        const float* __restrict__ d0,
                        const float* __restrict__ km,
                        const int* __restrict__ xp,
                        const int* __restrict__ yp,
                        float* __restrict__ abd)
{
    const int n = blockIdx.x * blockDim.x + threadIdx.x;
    if (n >= NN) return;
    const float* s = acc + n * 12;
    const double M00=s[0], M01=s[1], M02=s[2], M11=s[3], M12=s[4], M22=s[5];
    const double r0=s[6], r1=s[7], r2=s[8];
    const double cnt = M22;
    const double c00 = M11*M22 - M12*M12;
    const double c01 = M01*M22 - M12*M02;
    const double c02 = M01*M12 - M11*M02;
    const double det = M00*c00 - M01*c01 + M02*c02;
    const bool ok = (fabs(det) > 1e-8) && (cnt >= 3.0);
    float a = 0.f, b = 0.f, dc = 0.f, scale = 0.f;
    if (ok) {
        const double inv = 1.0 / det;
        const double t1 = r1*M22 - r2*M12;
        const double t2 = M01*r2 - r1*M02;
        const double x0 = (r0*c00 - M01*t1 + M02*(r1*M12 - r2*M11)) * inv;
        const double x1 = (M00*t1 - r0*c01 + M02*t2) * inv;
        const double x2 = (M00*(M11*r2 - r1*M12) - M01*t2 + r0*c02) * inv;
        a = (float)x0; b = (float)x1; dc = (float)x2;
        const float fx = km[0], fy = km[4];
        float sum = 0.0f;
        for (int k = 0; k < KK; ++k) {
            const int xi = xp[n*KK + k], yi = yp[n*KK + k];
            const float dd = d0[xi * W_ + yi];
            const float ad = fabsf(dd);
            const float ppx = (float)(yi - 320) * ad / fx;
            const float ppy = (float)(xi - 240) * ad / fy;
            const float den = a * ppx + b * ppy + dc;
            sum += dd / den;
        }
        scale = sum / (float)KK;
    }
    abd[n*8+0] = a; abd[n*8+1] = b; abd[n*8+2] = dc;
    abd[n*8+3] = scale;
    abd[n*8+4] = ok ? 1.0f : 0.0f;
}

// ---- scatter pass A: priority = max ok n per pixel, 4 queries/thread ------
__global__ __launch_bounds__(256) void prio_k(const int* __restrict__ xq,
                                              const int* __restrict__ yq,
                                              const float* __restrict__ abd,
                                              int* __restrict__ prio)
{
    const int idx = (blockIdx.x * 256 + threadIdx.x) * 4;   // QQ%4==0 -> same n
    const int n = idx >> 13;
    if (abd[n*8+4] == 0.0f) return;
    const int4 xs = *reinterpret_cast<const int4*>(xq + idx);
    const int4 ys = *reinterpret_cast<const int4*>(yq + idx);
    const int np = n + 1;
    atomicMax(prio + xs.x * W_ + ys.x, np);
    atomicMax(prio + xs.y * W_ + ys.y, np);
    atomicMax(prio + xs.z * W_ + ys.z, np);
    atomicMax(prio + xs.w * W_ + ys.w, np);
}

// ---- final: per pixel, winner n (or passthrough d0) -----------------------
__global__ __launch_bounds__(256) void final_k(const int* __restrict__ prio,
                                               const float* __restrict__ abd,
                                               const float* __restrict__ d0,
                                               const float* __restrict__ km,
                                               float* __restrict__ out)
{
    const int p0 = (blockIdx.x * 256 + threadIdx.x) * 4;
    const int4 pr4 = *reinterpret_cast<const int4*>(prio + p0);
    const float4 dv = *reinterpret_cast<const float4*>(d0 + p0);
    const float rfx = 1.0f / km[0], rfy = 1.0f / km[4];
    const int r = p0 / W_;
    const int c0 = p0 - r * W_;
    const float yv = (float)(r - 240) * rfy;
    const int pr[4] = {pr4.x, pr4.y, pr4.z, pr4.w};
    const float dd[4] = {dv.x, dv.y, dv.z, dv.w};
    float o[4];
    #pragma unroll
    for (int j = 0; j < 4; ++j) {
        float v = dd[j];
        if (pr[j] > 0) {
            const int n = pr[j] - 1;
            const float ad = fabsf(dd[j]);
            const float qx = (float)(c0 + j - 320) * ad * rfx;
            const float qy = yv * ad;
            v = (abd[n*8+0]*qx + abd[n*8+1]*qy + abd[n*8+2]) * abd[n*8+3];
        }
        o[j] = v;
    }
    *reinterpret_cast<float4*>(out + p0) = make_float4(o[0], o[1], o[2], o[3]);
}

extern "C" void kernel_launch(void* const* d_in, const int* in_sizes, int n_in,
                              void* d_out, int out_size, void* d_ws, size_t ws_size,
                              hipStream_t stream)
{
    const float* d0  = (const float*)d_in[0];
    const void*  gm  = d_in[1];
    const float* gtd = (const float*)d_in[2];
    const float* km  = (const float*)d_in[3];
    const void*  rm  = d_in[4];
    const int*   xq  = (const int*)d_in[5];
    const int*   yq  = (const int*)d_in[6];
    const int*   xp  = (const int*)d_in[7];
    const int*   yp  = (const int*)d_in[8];
    float* out = (float*)d_out;
    char*  ws  = (char*)d_ws;

    int* flag = (int*)(ws + WS_FLAG);
    float* acc = (float*)(ws + WS_ACC);
    float* abd = (float*)(ws + WS_ABD);
    unsigned long long* vbits = (unsigned long long*)(ws + WS_VBITS);
    int* prio = (int*)(ws + WS_PRIO);
    unsigned char* packed = (unsigned char*)(ws + WS_PACK);

    prep_k<<<HW / 256, 256, 0, stream>>>((const unsigned int*)gm, gtd, vbits, prio, acc, flag);
    if (ws_size >= WS_NEED) {
        compressA_k<<<CBLK, 256, 0, stream>>>(gm, flag, packed);
        compressB_k<<<CBLK, 256, 0, stream>>>(rm, flag, packed);
        reduce2_k<<<dim3(25, NN), 192, 0, stream>>>(d0, (const unsigned long long*)packed, vbits, km, acc);
    } else {
        reduce_k<<<dim3(HW / PIXB, NN), 256, 0, stream>>>(d0, gm, rm, km, flag, vbits, acc);
    }
    solve_k<<<2, 64, 0, stream>>>(acc, d0, km, xp, yp, abd);
    prio_k<<<(NN * QQ / 4) / 256, 256, 0, stream>>>(xq, yq, abd, prio);
    final_k<<<(HW / 4) / 256, 256, 0, stream>>>(prio, abd, d0, km, out);
}

// Round 14
// 128.027 us; speedup vs baseline: 1.0575x; 1.0575x over previous
//
#include <hip/hip_runtime.h>

#define H_ 480
#define W_ 640
#define HW 307200
#define NN 128
#define QQ 8192
#define KK 10
#define G_ 6
#define PIXB 6144   // legacy path: 256 threads * 4 px * G_ iters

// ws layout (bytes)
#define WS_FLAG   0
#define WS_ACC    64            // 128*12 floats = 6144 B
#define WS_ABD    8192          // 128*8 floats  = 4096 B
#define WS_VBITS  16384         // 4800 * 8      = 38400 B
#define WS_PRIO   65536         // 307200*4 = 1228800 B
#define WS_PACK   1294336       // NN*38400 = 4915200 B (1 byte per 8 px)
#define WS_NEED   (WS_PACK + (size_t)NN * 38400)

#define NCHUNK 38400            // 4KB chunks per mask (157 MB / 4 KB)
#define CBLK2  2048

#define AS1 __attribute__((address_space(1)))
#define AS3 __attribute__((address_space(3)))

typedef unsigned int u32x4 __attribute__((ext_vector_type(4)));

// ---- prep: detect mask format (block 0), pack valid bits, zero prio/acc ---
__global__ __launch_bounds__(256) void prep_k(const unsigned int* __restrict__ gm,
                                              const float* __restrict__ gtd,
                                              unsigned long long* __restrict__ vbits,
                                              int* __restrict__ prio,
                                              float* __restrict__ acc,
                                              int* __restrict__ flag)
{
    const int pix = blockIdx.x * 256 + threadIdx.x;
    prio[pix] = 0;
    if (pix < NN * 12) acc[pix] = 0.0f;
    const bool v = gtd[pix] > 0.1f;
    const unsigned long long b = __ballot(v);
    if ((threadIdx.x & 63) == 0) vbits[pix >> 6] = b;

    if (blockIdx.x == 0) {
        // int32: every word 0/1. uint8: words >1 (but != 0x3F800000) common.
        // float32: words 0x0 or 0x3F800000.
        __shared__ int sf;
        if (threadIdx.x == 0) sf = 0;
        __syncthreads();
        int f = 0;
        for (int i = threadIdx.x; i < 4096; i += 256) {
            const unsigned int w = gm[i];
            if (w == 0x3F800000u) f |= 2;
            else if (w > 1u) f |= 1;
        }
        if (f) atomicOr(&sf, f);
        __syncthreads();
        if (threadIdx.x == 0) *flag = (sf & 2) ? 2 : ((sf & 1) ? 1 : 0);
    }
}

__device__ __forceinline__ unsigned nib4v(const u32x4 a, const u32x4 b)
{
    return ((a.x & b.x) ? 1u : 0u) | ((a.y & b.y) ? 2u : 0u)
         | ((a.z & b.z) ? 4u : 0u) | ((a.w & b.w) ? 8u : 0u);
}

__device__ __forceinline__ unsigned nib4(const uint4& a, const uint4& b)
{
    return ((a.x & b.x) ? 1u : 0u) | ((a.y & b.y) ? 2u : 0u)
         | ((a.z & b.z) ? 4u : 0u) | ((a.w & b.w) ? 8u : 0u);
}

// ---- pass 1: LDS-DMA stream — masks -> 1 byte per 8 px --------------------
// Per iter: stage 4KB gm + 4KB rm via global_load_lds width=16 (direct-to-LDS
// DMA, no VGPR return), barrier (vmcnt drain), pack from LDS, 1 byte store.
__global__ __launch_bounds__(256) void compress_k(
    const void* __restrict__ gmv,
    const void* __restrict__ rmv,
    const int* __restrict__ flag,
    unsigned char* __restrict__ packed)
{
    const int fmt = *flag;
    const int t = (int)threadIdx.x;

    if (fmt != 1) {
        // 4-byte elements (int32 0/1 or float32 0.0/1.0): (a&b)!=0 == both-true
        __shared__ char lds[8192];
        char* ldsA = lds + (t >> 6) * 1024;          // wave-uniform base, gm
        char* ldsB = lds + 4096 + (t >> 6) * 1024;   // wave-uniform base, rm
        for (int c = blockIdx.x; c < NCHUNK; c += CBLK2) {
            const char* gsrc = (const char*)gmv + (size_t)c * 4096 + (size_t)t * 16;
            const char* rsrc = (const char*)rmv + (size_t)c * 4096 + (size_t)t * 16;
            __builtin_amdgcn_global_load_lds((const AS1 unsigned*)gsrc,
                                             (AS3 unsigned*)ldsA, 16, 0, 0);
            __builtin_amdgcn_global_load_lds((const AS1 unsigned*)rsrc,
                                             (AS3 unsigned*)ldsB, 16, 0, 0);
            __syncthreads();                          // drains vmcnt(0)
            const u32x4 a = *reinterpret_cast<const u32x4*>(lds + t * 16);
            const u32x4 b = *reinterpret_cast<const u32x4*>(lds + 4096 + t * 16);
            const unsigned m = nib4v(a, b);
            const unsigned hi = __shfl_down(m, 1);
            if (!(t & 1))
                packed[c * 128 + (t >> 1)] = (unsigned char)(m | (hi << 4));
            __syncthreads();                          // LDS reuse next iter
        }
    } else {
        // 1-byte elements (bool as uint8) — plain dense u64 loads
        const unsigned long long* __restrict__ gp = (const unsigned long long*)gmv;
        const unsigned long long* __restrict__ rp = (const unsigned long long*)rmv;
        const int tid0 = blockIdx.x * 256 + t;
        for (int g = tid0; g < NN * HW / 8; g += CBLK2 * 256) {
            const unsigned long long ab = gp[g] & rp[g];
            unsigned m = 0;
            #pragma unroll
            for (int j = 0; j < 8; ++j)
                m |= (unsigned)(((ab >> (8*j)) & 0xFFull) != 0) << j;
            packed[g] = (unsigned char)m;
        }
    }
}

// ---- pass 2: per (word-chunk, n) accumulate M, rhs from packed bytes ------
// grid (25, NN), 192 threads; one u64 word (64 px) per thread. 25*192=4800.
__global__ __launch_bounds__(192) void reduce2_k(
    const float* __restrict__ d0,
    const unsigned long long* __restrict__ packed,
    const unsigned long long* __restrict__ vbits,
    const float* __restrict__ km,
    float* __restrict__ acc)
{
    const int n = blockIdx.y;
    const int w = blockIdx.x * 192 + (int)threadIdx.x;   // word index, 0..4799
    unsigned long long bits = packed[(size_t)n * 4800 + w] & vbits[w];
    const float rfx = 1.0f / km[0], rfy = 1.0f / km[4];

    float s0=0.f,s1=0.f,s2=0.f,s3=0.f,s4=0.f,s5=0.f,s6=0.f,s7=0.f,s8=0.f;
    if (bits) {
        const int r = w / 10;                  // 10 words per row (640/64)
        const int c0 = (w - r * 10) * 64;
        const float pyb = (float)(r - 240) * rfy;
        const float* drow = d0 + r * W_ + c0;
        while (bits) {
            const int j = __ffsll((unsigned long long)bits) - 1;
            bits &= bits - 1;
            const float d = drow[j];
            const float ad = fabsf(d);
            const float px = (float)(c0 + j - 320) * ad * rfx;
            const float py = pyb * ad;
            s0 += px*px; s1 += px*py; s2 += px;
            s3 += py*py; s4 += py;    s5 += 1.0f;
            s6 += px*d;  s7 += py*d;  s8 += d;
        }
    }

    float s[9] = {s0,s1,s2,s3,s4,s5,s6,s7,s8};
    #pragma unroll
    for (int off = 32; off > 0; off >>= 1) {
        #pragma unroll
        for (int i = 0; i < 9; ++i) s[i] += __shfl_down(s[i], off);
    }
    __shared__ float ls[3][9];
    const int wave = threadIdx.x >> 6, lane = threadIdx.x & 63;
    if (lane == 0) {
        #pragma unroll
        for (int i = 0; i < 9; ++i) ls[wave][i] = s[i];
    }
    __syncthreads();
    if (threadIdx.x < 9) {
        const int i = threadIdx.x;
        atomicAdd(&acc[n*12 + i], ls[0][i] + ls[1][i] + ls[2][i]);
    }
}

// ---- legacy fused reduction (fallback if ws too small) --------------------
__global__ __launch_bounds__(256) void reduce_k(
    const float* __restrict__ d0,
    const void* __restrict__ gmv,
    const void* __restrict__ rmv,
    const float* __restrict__ km,
    const int* __restrict__ flag,
    const unsigned long long* __restrict__ vbits,
    float* __restrict__ acc)
{
    const int n = blockIdx.y;
    const int base = blockIdx.x * PIXB + (int)threadIdx.x * 4;
    const int fmt = *flag;
    const float rfx = 1.0f / km[0], rfy = 1.0f / km[4];
    const size_t moff = (size_t)n * HW;

    unsigned bitsArr[G_];
    if (fmt != 1) {
        uint4 ga[G_], ra[G_];
        #pragma unroll
        for (int g = 0; g < G_; ++g) {
            const int p = base + g * 1024;
            ga[g] = *reinterpret_cast<const uint4*>((const unsigned*)gmv + moff + p);
            ra[g] = *reinterpret_cast<const uint4*>((const unsigned*)rmv + moff + p);
        }
        #pragma unroll
        for (int g = 0; g < G_; ++g) bitsArr[g] = nib4(ga[g], ra[g]);
    } else {
        unsigned ga[G_], ra[G_];
        #pragma unroll
        for (int g = 0; g < G_; ++g) {
            const int p = base + g * 1024;
            ga[g] = *reinterpret_cast<const unsigned*>((const unsigned char*)gmv + moff + p);
            ra[g] = *reinterpret_cast<const unsigned*>((const unsigned char*)rmv + moff + p);
        }
        #pragma unroll
        for (int g = 0; g < G_; ++g) {
            const unsigned ab = ga[g] & ra[g];
            bitsArr[g] = (unsigned)((ab & 0xFFu) != 0) | ((unsigned)(((ab>>8) & 0xFFu) != 0) << 1)
                       | ((unsigned)(((ab>>16) & 0xFFu) != 0) << 2) | ((unsigned)((ab>>24) != 0) << 3);
        }
    }

    float s0=0.f,s1=0.f,s2=0.f,s3=0.f,s4=0.f,s5=0.f,s6=0.f,s7=0.f,s8=0.f;
    #pragma unroll
    for (int g = 0; g < G_; ++g) {
        const int p0 = base + g * 1024;
        unsigned bits = bitsArr[g] & ((unsigned)(vbits[p0 >> 6] >> (p0 & 63)) & 0xFu);
        if (bits) {
            const float4 dv = *reinterpret_cast<const float4*>(d0 + p0);
            const int r = p0 / W_;
            const int c0 = p0 - r * W_;
            const float pyb = (float)(r - 240) * rfy;
            while (bits) {
                const int j = __ffs(bits) - 1;
                bits &= bits - 1;
                const float d = (j == 0) ? dv.x : (j == 1) ? dv.y : (j == 2) ? dv.z : dv.w;
                const float ad = fabsf(d);
                const float px = (float)(c0 + j - 320) * ad * rfx;
                const float py = pyb * ad;
                s0 += px*px; s1 += px*py; s2 += px;
                s3 += py*py; s4 += py;    s5 += 1.0f;
                s6 += px*d;  s7 += py*d;  s8 += d;
            }
        }
    }

    float s[9] = {s0,s1,s2,s3,s4,s5,s6,s7,s8};
    #pragma unroll
    for (int off = 32; off > 0; off >>= 1) {
        #pragma unroll
        for (int i = 0; i < 9; ++i) s[i] += __shfl_down(s[i], off);
    }
    __shared__ float ls[4][9];
    const int wave = threadIdx.x >> 6, lane = threadIdx.x & 63;
    if (lane == 0) {
        #pragma unroll
        for (int i = 0; i < 9; ++i) ls[wave][i] = s[i];
    }
    __syncthreads();
    if (threadIdx.x == 0) {
        #pragma unroll
        for (int i = 0; i < 9; ++i)
            atomicAdd(&acc[n*12 + i], ls[0][i] + ls[1][i] + ls[2][i] + ls[3][i]);
    }
}

// ---- per-n 3x3 solve (Cramer, double), ok gate, mean(pd/den) --------------
__global__ void solve_k(const float* __restrict__ acc,
                        const float* __restrict__ d0,
                        const float* __restrict__ km,
                        const int* __restrict__ xp,
                        const int* __restrict__ yp,
                        float* __restrict__ abd)
{
    const int n = blockIdx.x * blockDim.x + threadIdx.x;
    if (n >= NN) return;
    const float* s = acc + n * 12;
    const double M00=s[0], M01=s[1], M02=s[2], M11=s[3], M12=s[4], M22=s[5];
    const double r0=s[6], r1=s[7], r2=s[8];
    const double cnt = M22;
    const double c00 = M11*M22 - M12*M12;
    const double c01 = M01*M22 - M12*M02;
    const double c02 = M01*M12 - M11*M02;
    const double det = M00*c00 - M01*c01 + M02*c02;
    const bool ok = (fabs(det) > 1e-8) && (cnt >= 3.0);
    float a = 0.f, b = 0.f, dc = 0.f, scale = 0.f;
    if (ok) {
        const double inv = 1.0 / det;
        const double t1 = r1*M22 - r2*M12;
        const double t2 = M01*r2 - r1*M02;
        const double x0 = (r0*c00 - M01*t1 + M02*(r1*M12 - r2*M11)) * inv;
        const double x1 = (M00*t1 - r0*c01 + M02*t2) * inv;
        const double x2 = (M00*(M11*r2 - r1*M12) - M01*t2 + r0*c02) * inv;
        a = (float)x0; b = (float)x1; dc = (float)x2;
        const float fx = km[0], fy = km[4];
        float sum = 0.0f;
        for (int k = 0; k < KK; ++k) {
            const int xi = xp[n*KK + k], yi = yp[n*KK + k];
            const float dd = d0[xi * W_ + yi];
            const float ad = fabsf(dd);
            const float ppx = (float)(yi - 320) * ad / fx;
            const float ppy = (float)(xi - 240) * ad / fy;
            const float den = a * ppx + b * ppy + dc;
            sum += dd / den;
        }
        scale = sum / (float)KK;
    }
    abd[n*8+0] = a; abd[n*8+1] = b; abd[n*8+2] = dc;
    abd[n*8+3] = scale;
    abd[n*8+4] = ok ? 1.0f : 0.0f;
}

// ---- scatter pass A: priority = max ok n per pixel, 4 queries/thread ------
__global__ __launch_bounds__(256) void prio_k(const int* __restrict__ xq,
                                              const int* __restrict__ yq,
                                              const float* __restrict__ abd,
                                              int* __restrict__ prio)
{
    const int idx = (blockIdx.x * 256 + threadIdx.x) * 4;   // QQ%4==0 -> same n
    const int n = idx >> 13;
    if (abd[n*8+4] == 0.0f) return;
    const int4 xs = *reinterpret_cast<const int4*>(xq + idx);
    const int4 ys = *reinterpret_cast<const int4*>(yq + idx);
    const int np = n + 1;
    atomicMax(prio + xs.x * W_ + ys.x, np);
    atomicMax(prio + xs.y * W_ + ys.y, np);
    atomicMax(prio + xs.z * W_ + ys.z, np);
    atomicMax(prio + xs.w * W_ + ys.w, np);
}

// ---- final: per pixel, winner n (or passthrough d0) -----------------------
__global__ __launch_bounds__(256) void final_k(const int* __restrict__ prio,
                                               const float* __restrict__ abd,
                                               const float* __restrict__ d0,
                                               const float* __restrict__ km,
                                               float* __restrict__ out)
{
    const int p0 = (blockIdx.x * 256 + threadIdx.x) * 4;
    const int4 pr4 = *reinterpret_cast<const int4*>(prio + p0);
    const float4 dv = *reinterpret_cast<const float4*>(d0 + p0);
    const float rfx = 1.0f / km[0], rfy = 1.0f / km[4];
    const int r = p0 / W_;
    const int c0 = p0 - r * W_;
    const float yv = (float)(r - 240) * rfy;
    const int pr[4] = {pr4.x, pr4.y, pr4.z, pr4.w};
    const float dd[4] = {dv.x, dv.y, dv.z, dv.w};
    float o[4];
    #pragma unroll
    for (int j = 0; j < 4; ++j) {
        float v = dd[j];
        if (pr[j] > 0) {
            const int n = pr[j] - 1;
            const float ad = fabsf(dd[j]);
            const float qx = (float)(c0 + j - 320) * ad * rfx;
            const float qy = yv * ad;
            v = (abd[n*8+0]*qx + abd[n*8+1]*qy + abd[n*8+2]) * abd[n*8+3];
        }
        o[j] = v;
    }
    *reinterpret_cast<float4*>(out + p0) = make_float4(o[0], o[1], o[2], o[3]);
}

extern "C" void kernel_launch(void* const* d_in, const int* in_sizes, int n_in,
                              void* d_out, int out_size, void* d_ws, size_t ws_size,
                              hipStream_t stream)
{
    const float* d0  = (const float*)d_in[0];
    const void*  gm  = d_in[1];
    const float* gtd = (const float*)d_in[2];
    const float* km  = (const float*)d_in[3];
    const void*  rm  = d_in[4];
    const int*   xq  = (const int*)d_in[5];
    const int*   yq  = (const int*)d_in[6];
    const int*   xp  = (const int*)d_in[7];
    const int*   yp  = (const int*)d_in[8];
    float* out = (float*)d_out;
    char*  ws  = (char*)d_ws;

    int* flag = (int*)(ws + WS_FLAG);
    float* acc = (float*)(ws + WS_ACC);
    float* abd = (float*)(ws + WS_ABD);
    unsigned long long* vbits = (unsigned long long*)(ws + WS_VBITS);
    int* prio = (int*)(ws + WS_PRIO);
    unsigned char* packed = (unsigned char*)(ws + WS_PACK);

    prep_k<<<HW / 256, 256, 0, stream>>>((const unsigned int*)gm, gtd, vbits, prio, acc, flag);
    if (ws_size >= WS_NEED) {
        compress_k<<<CBLK2, 256, 0, stream>>>(gm, rm, flag, packed);
        reduce2_k<<<dim3(25, NN), 192, 0, stream>>>(d0, (const unsigned long long*)packed, vbits, km, acc);
    } else {
        reduce_k<<<dim3(HW / PIXB, NN), 256, 0, stream>>>(d0, gm, rm, km, flag, vbits, acc);
    }
    solve_k<<<2, 64, 0, stream>>>(acc, d0, km, xp, yp, abd);
    prio_k<<<(NN * QQ / 4) / 256, 256, 0, stream>>>(xq, yq, abd, prio);
    final_k<<<(HW / 4) / 256, 256, 0, stream>>>(prio, abd, d0, km, out);
}

// Round 16
// 116.906 us; speedup vs baseline: 1.1581x; 1.0951x over previous
//
#include <hip/hip_runtime.h>

#define H_ 480
#define W_ 640
#define HW 307200
#define NN 128
#define QQ 8192
#define KK 10

// ws layout (bytes)
#define WS_FLAG   0
#define WS_ACC    64            // 128*12 floats = 6144 B
#define WS_ABD    8192          // 128*8 floats  = 4096 B
#define WS_VBITS  16384         // 4800*8 = 38400 B  (legacy path)
#define WS_VNIB   57344        // 76800 B (valid nibble per 4 px)
#define WS_PRIO   196608        // 307200*4 = 1228800 B
#define WS_NEED   (WS_PRIO + (size_t)HW * 4)

typedef unsigned int u32x4 __attribute__((ext_vector_type(4)));

// ---- prep: detect mask format (block 0), valid bits+nibbles, zero structs -
__global__ __launch_bounds__(256) void prep_k(const unsigned int* __restrict__ gm,
                                              const float* __restrict__ gtd,
                                              unsigned long long* __restrict__ vbits,
                                              unsigned char* __restrict__ vnib,
                                              int* __restrict__ prio,
                                              float* __restrict__ acc,
                                              int* __restrict__ flag)
{
    const int pix = blockIdx.x * 256 + threadIdx.x;
    prio[pix] = 0;
    if (pix < NN * 12) acc[pix] = 0.0f;
    const bool v = gtd[pix] > 0.1f;
    const unsigned long long b = __ballot(v);
    const int lane = threadIdx.x & 63;
    if (lane == 0) vbits[pix >> 6] = b;
    if ((lane & 3) == 0) vnib[pix >> 2] = (unsigned char)((b >> lane) & 0xFull);

    if (blockIdx.x == 0) {
        // int32: every word 0/1. uint8: words >1 (but != 0x3F800000) common.
        // float32: words 0x0 or 0x3F800000.
        __shared__ int sf;
        if (threadIdx.x == 0) sf = 0;
        __syncthreads();
        int f = 0;
        for (int i = threadIdx.x; i < 4096; i += 256) {
            const unsigned int w = gm[i];
            if (w == 0x3F800000u) f |= 2;
            else if (w > 1u) f |= 1;
        }
        if (f) atomicOr(&sf, f);
        __syncthreads();
        if (threadIdx.x == 0) *flag = (sf & 2) ? 2 : ((sf & 1) ? 1 : 0);
    }
}

__device__ __forceinline__ unsigned nib4v(const u32x4 a, const u32x4 b)
{
    return ((a.x & b.x) ? 1u : 0u) | ((a.y & b.y) ? 2u : 0u)
         | ((a.z & b.z) ? 4u : 0u) | ((a.w & b.w) ? 8u : 0u);
}

// ---- fused mask-stream + reduction: grid (25, NN), 256 thr, 12 iters ------
// Per iter: 2 dense 16B nt-loads -> nibble AND vnib -> rare ffs/FMA on
// active px. 9 partial sums, one butterfly + 9 atomics per block.
__global__ __launch_bounds__(256) void reduce3_k(
    const float* __restrict__ d0,
    const void* __restrict__ gmv,
    const void* __restrict__ rmv,
    const unsigned char* __restrict__ vnib,
    const int* __restrict__ flag,
    const float* __restrict__ km,
    float* __restrict__ acc)
{
    const int n = blockIdx.y;
    const int fmt = *flag;
    const float rfx = 1.0f / km[0], rfy = 1.0f / km[4];

    float s0=0.f,s1=0.f,s2=0.f,s3=0.f,s4=0.f,s5=0.f,s6=0.f,s7=0.f,s8=0.f;

    for (int it = 0; it < 12; ++it) {
        const int g = blockIdx.x * 3072 + it * 256 + (int)threadIdx.x; // nibble idx, 0..76799
        unsigned bits;
        if (fmt != 1) {
            // 4-byte elements (int32 0/1 or float32 0.0/1.0)
            const u32x4* gp = (const u32x4*)gmv + (size_t)n * (HW/4);
            const u32x4* rp = (const u32x4*)rmv + (size_t)n * (HW/4);
            const u32x4 a = __builtin_nontemporal_load(gp + g);
            const u32x4 b = __builtin_nontemporal_load(rp + g);
            bits = nib4v(a, b);
        } else {
            // 1-byte elements: 4 px per u32
            const unsigned* gp = (const unsigned*)gmv + (size_t)n * (HW/4);
            const unsigned* rp = (const unsigned*)rmv + (size_t)n * (HW/4);
            const unsigned ab = __builtin_nontemporal_load(gp + g)
                              & __builtin_nontemporal_load(rp + g);
            bits = (unsigned)((ab & 0xFFu) != 0)
                 | ((unsigned)(((ab >> 8) & 0xFFu) != 0) << 1)
                 | ((unsigned)(((ab >> 16) & 0xFFu) != 0) << 2)
                 | ((unsigned)((ab >> 24) != 0) << 3);
        }
        bits &= vnib[g];
        if (bits) {
            const int p0 = g * 4;
            const float4 dv = *reinterpret_cast<const float4*>(d0 + p0);
            const int r = p0 / W_;                 // 640%4==0: no row straddle
            const int c0 = p0 - r * W_;
            const float pyb = (float)(r - 240) * rfy;
            while (bits) {
                const int j = __ffs(bits) - 1;
                bits &= bits - 1;
                const float d = (j == 0) ? dv.x : (j == 1) ? dv.y : (j == 2) ? dv.z : dv.w;
                const float ad = fabsf(d);
                const float px = (float)(c0 + j - 320) * ad * rfx;
                const float py = pyb * ad;
                s0 += px*px; s1 += px*py; s2 += px;
                s3 += py*py; s4 += py;    s5 += 1.0f;
                s6 += px*d;  s7 += py*d;  s8 += d;
            }
        }
    }

    float s[9] = {s0,s1,s2,s3,s4,s5,s6,s7,s8};
    #pragma unroll
    for (int off = 32; off > 0; off >>= 1) {
        #pragma unroll
        for (int i = 0; i < 9; ++i) s[i] += __shfl_down(s[i], off);
    }
    __shared__ float ls[4][9];
    const int wave = threadIdx.x >> 6, lane = threadIdx.x & 63;
    if (lane == 0) {
        #pragma unroll
        for (int i = 0; i < 9; ++i) ls[wave][i] = s[i];
    }
    __syncthreads();
    if (threadIdx.x < 9) {
        const int i = threadIdx.x;
        atomicAdd(&acc[n*12 + i], ls[0][i] + ls[1][i] + ls[2][i] + ls[3][i]);
    }
}

// ---- per-n 3x3 solve (Cramer, double), ok gate, mean(pd/den) --------------
__global__ void solve_k(const float* __restrict__ acc,
                        const float* __restrict__ d0,
                        const float* __restrict__ km,
                        const int* __restrict__ xp,
                        const int* __restrict__ yp,
                        float* __restrict__ abd)
{
    const int n = blockIdx.x * blockDim.x + threadIdx.x;
    if (n >= NN) return;
    const float* s = acc + n * 12;
    const double M00=s[0], M01=s[1], M02=s[2], M11=s[3], M12=s[4], M22=s[5];
    const double r0=s[6], r1=s[7], r2=s[8];
    const double cnt = M22;
    const double c00 = M11*M22 - M12*M12;
    const double c01 = M01*M22 - M12*M02;
    const double c02 = M01*M12 - M11*M02;
    const double det = M00*c00 - M01*c01 + M02*c02;
    const bool ok = (fabs(det) > 1e-8) && (cnt >= 3.0);
    float a = 0.f, b = 0.f, dc = 0.f, scale = 0.f;
    if (ok) {
        const double inv = 1.0 / det;
        const double t1 = r1*M22 - r2*M12;
        const double t2 = M01*r2 - r1*M02;
        const double x0 = (r0*c00 - M01*t1 + M02*(r1*M12 - r2*M11)) * inv;
        const double x1 = (M00*t1 - r0*c01 + M02*t2) * inv;
        const double x2 = (M00*(M11*r2 - r1*M12) - M01*t2 + r0*c02) * inv;
        a = (float)x0; b = (float)x1; dc = (float)x2;
        const float fx = km[0], fy = km[4];
        float sum = 0.0f;
        for (int k = 0; k < KK; ++k) {
            const int xi = xp[n*KK + k], yi = yp[n*KK + k];
            const float dd = d0[xi * W_ + yi];
            const float ad = fabsf(dd);
            const float ppx = (float)(yi - 320) * ad / fx;
            const float ppy = (float)(xi - 240) * ad / fy;
            const float den = a * ppx + b * ppy + dc;
            sum += dd / den;
        }
        scale = sum / (float)KK;
    }
    abd[n*8+0] = a; abd[n*8+1] = b; abd[n*8+2] = dc;
    abd[n*8+3] = scale;
    abd[n*8+4] = ok ? 1.0f : 0.0f;
}

// ---- scatter pass A: priority = max ok n per pixel, 4 queries/thread ------
__global__ __launch_bounds__(256) void prio_k(const int* __restrict__ xq,
                                              const int* __restrict__ yq,
                                              const float* __restrict__ abd,
                                              int* __restrict__ prio)
{
    const int idx = (blockIdx.x * 256 + threadIdx.x) * 4;   // QQ%4==0 -> same n
    const int n = idx >> 13;
    if (abd[n*8+4] == 0.0f) return;
    const int4 xs = *reinterpret_cast<const int4*>(xq + idx);
    const int4 ys = *reinterpret_cast<const int4*>(yq + idx);
    const int np = n + 1;
    atomicMax(prio + xs.x * W_ + ys.x, np);
    atomicMax(prio + xs.y * W_ + ys.y, np);
    atomicMax(prio + xs.z * W_ + ys.z, np);
    atomicMax(prio + xs.w * W_ + ys.w, np);
}

// ---- final: per pixel, winner n (or passthrough d0) -----------------------
__global__ __launch_bounds__(256) void final_k(const int* __restrict__ prio,
                                               const float* __restrict__ abd,
                                               const float* __restrict__ d0,
                                               const float* __restrict__ km,
                                               float* __restrict__ out)
{
    const int p0 = (blockIdx.x * 256 + threadIdx.x) * 4;
    const int4 pr4 = *reinterpret_cast<const int4*>(prio + p0);
    const float4 dv = *reinterpret_cast<const float4*>(d0 + p0);
    const float rfx = 1.0f / km[0], rfy = 1.0f / km[4];
    const int r = p0 / W_;
    const int c0 = p0 - r * W_;
    const float yv = (float)(r - 240) * rfy;
    const int pr[4] = {pr4.x, pr4.y, pr4.z, pr4.w};
    const float dd[4] = {dv.x, dv.y, dv.z, dv.w};
    float o[4];
    #pragma unroll
    for (int j = 0; j < 4; ++j) {
        float v = dd[j];
        if (pr[j] > 0) {
            const int n = pr[j] - 1;
            const float ad = fabsf(dd[j]);
            const float qx = (float)(c0 + j - 320) * ad * rfx;
            const float qy = yv * ad;
            v = (abd[n*8+0]*qx + abd[n*8+1]*qy + abd[n*8+2]) * abd[n*8+3];
        }
        o[j] = v;
    }
    *reinterpret_cast<float4*>(out + p0) = make_float4(o[0], o[1], o[2], o[3]);
}

extern "C" void kernel_launch(void* const* d_in, const int* in_sizes, int n_in,
                              void* d_out, int out_size, void* d_ws, size_t ws_size,
                              hipStream_t stream)
{
    const float* d0  = (const float*)d_in[0];
    const void*  gm  = d_in[1];
    const float* gtd = (const float*)d_in[2];
    const float* km  = (const float*)d_in[3];
    const void*  rm  = d_in[4];
    const int*   xq  = (const int*)d_in[5];
    const int*   yq  = (const int*)d_in[6];
    const int*   xp  = (const int*)d_in[7];
    const int*   yp  = (const int*)d_in[8];
    float* out = (float*)d_out;
    char*  ws  = (char*)d_ws;

    int* flag = (int*)(ws + WS_FLAG);
    float* acc = (float*)(ws + WS_ACC);
    float* abd = (float*)(ws + WS_ABD);
    unsigned long long* vbits = (unsigned long long*)(ws + WS_VBITS);
    unsigned char* vnib = (unsigned char*)(ws + WS_VNIB);
    int* prio = (int*)(ws + WS_PRIO);

    prep_k<<<HW / 256, 256, 0, stream>>>((const unsigned int*)gm, gtd, vbits, vnib, prio, acc, flag);
    reduce3_k<<<dim3(25, NN), 256, 0, stream>>>(d0, gm, rm, vnib, flag, km, acc);
    solve_k<<<2, 64, 0, stream>>>(acc, d0, km, xp, yp, abd);
    prio_k<<<(NN * QQ / 4) / 256, 256, 0, stream>>>(xq, yq, abd, prio);
    final_k<<<(HW / 4) / 256, 256, 0, stream>>>(prio, abd, d0, km, out);
}